// Round 7
// baseline (6021.690 us; speedup 1.0000x reference)
//
#include <hip/hip_runtime.h>
#include <stdint.h>

#define T_ 1024
#define B_ 64
#define I_ 256
#define H_ 512
#define O_ 5
#define NB 8             // batches per chain
#define JGW 8            // j-cols per wave (one 16B publish sector per batch)
#define GRID_MAIN 512    // 8 chains x 64 jgroups; 1 wave per block
#define BLOCK_MAIN 64
#define EX_OFF 4096      // hist offset in ws (bytes)
#define BH (B_*H_)
#define TBO (T_*B_*O_)
#define HIST_BYTES ((size_t)(T_+1)*BH*2)
#define POISON 0x7F7F7F7Fu   // bf16 pair sentinel: |h|<1 can never encode 0x7F7F

typedef __bf16 bf16x8 __attribute__((ext_vector_type(8)));
typedef float floatx4 __attribute__((ext_vector_type(4)));
typedef unsigned short u16;
typedef unsigned short u16x8 __attribute__((ext_vector_type(8)));
typedef unsigned int u32;
typedef u32 u32x4 __attribute__((ext_vector_type(4)));

__device__ __forceinline__ u16 f2bf(float f) {
  unsigned int u = __float_as_uint(f);
  u += 0x7fffu + ((u >> 16) & 1u);   // RNE
  return (u16)(u >> 16);
}
__device__ __forceinline__ float bf2f(u16 v) {
  return __uint_as_float(((unsigned int)v) << 16);
}
__device__ __forceinline__ float sigmoid_f(float x) {
  return 1.0f / (1.0f + __expf(-x));
}
__device__ __forceinline__ float tanh_f(float x) {
  return 2.0f / (1.0f + __expf(-2.0f * x)) - 1.0f;
}

// ---- L3-coherent exchange (sc0 sc1 = bypass L1/L2; coherence point is the
// memory-side Infinity Cache). Write-once + sentinel slots: any non-poison
// value read is correct; staleness can only look like poison -> retry.
__device__ __forceinline__ void store_u32x4_l3(u32* p, u32x4 v) {
  asm volatile("global_store_dwordx4 %0, %1, off sc0 sc1" :: "v"(p), "v"(v) : "memory");
}

// poll ALL 16 h-chunks of the chain (per lane: 16 x 16B, stride 64B within
// the batch row) — all issued, ONE vmcnt => one L3 round trip per try.
__device__ __forceinline__ void load_h16_l3(const u16* p, u32x4* r) {
  asm volatile(
    "global_load_dwordx4 %0, %8, off sc0 sc1\n\t"
    "global_load_dwordx4 %1, %8, off offset:64 sc0 sc1\n\t"
    "global_load_dwordx4 %2, %8, off offset:128 sc0 sc1\n\t"
    "global_load_dwordx4 %3, %8, off offset:192 sc0 sc1\n\t"
    "global_load_dwordx4 %4, %8, off offset:256 sc0 sc1\n\t"
    "global_load_dwordx4 %5, %8, off offset:320 sc0 sc1\n\t"
    "global_load_dwordx4 %6, %8, off offset:384 sc0 sc1\n\t"
    "global_load_dwordx4 %7, %8, off offset:448 sc0 sc1"
    : "=&v"(r[0]), "=&v"(r[1]), "=&v"(r[2]), "=&v"(r[3]),
      "=&v"(r[4]), "=&v"(r[5]), "=&v"(r[6]), "=&v"(r[7])
    : "v"(p) : "memory");
  asm volatile(
    "global_load_dwordx4 %0, %8, off offset:512 sc0 sc1\n\t"
    "global_load_dwordx4 %1, %8, off offset:576 sc0 sc1\n\t"
    "global_load_dwordx4 %2, %8, off offset:640 sc0 sc1\n\t"
    "global_load_dwordx4 %3, %8, off offset:704 sc0 sc1\n\t"
    "global_load_dwordx4 %4, %8, off offset:768 sc0 sc1\n\t"
    "global_load_dwordx4 %5, %8, off offset:832 sc0 sc1\n\t"
    "global_load_dwordx4 %6, %8, off offset:896 sc0 sc1\n\t"
    "global_load_dwordx4 %7, %8, off offset:960 sc0 sc1\n\t"
    "s_waitcnt vmcnt(0)"
    : "=&v"(r[8]), "=&v"(r[9]), "=&v"(r[10]), "=&v"(r[11]),
      "=&v"(r[12]), "=&v"(r[13]), "=&v"(r[14]), "=&v"(r[15])
    : "v"(p) : "memory");
}

// x -> bf16 pre-conversion (one-time parallel pass; removes per-step f32
// loads + f2bf from the serial loop). 8 floats/thread.
__global__ __launch_bounds__(256)
void xconv_kernel(const float* __restrict__ x, u16* __restrict__ xbf) {
  const size_t idx = (size_t)blockIdx.x * 256 + threadIdx.x;  // chunk of 8
  const float4* s = (const float4*)x + 2 * idx;
  float4 f0 = s[0], f1 = s[1];
  u16x8 uu;
  uu[0]=f2bf(f0.x); uu[1]=f2bf(f0.y); uu[2]=f2bf(f0.z); uu[3]=f2bf(f0.w);
  uu[4]=f2bf(f1.x); uu[5]=f2bf(f1.y); uu[6]=f2bf(f1.z); uu[7]=f2bf(f1.w);
  ((u16x8*)xbf)[idx] = uu;
}

// Persistent LSTM, R7 structure: 512 INDEPENDENT single-wave blocks
// (8 chains x 64 jgroups of 8 cols). Each wave: full K=768 for its 8 j-cols
// (2 M-tiles, R5-verified interleaved row map -> all 4 gates in-lane), so
// there is NO intra-WG communication: no LDS, no barriers, no reduce. Per
// step: issue x loads -> sentinel-poll all 16 h-chunks (1 L3 RT/try) ->
// 48 MFMAs (8 indep acc chains) -> elementwise -> 3 shuffles -> ONE 16B
// sector-aligned publish per batch row.
__global__ __launch_bounds__(BLOCK_MAIN, 1)
void lstm_persistent(const u16* __restrict__ xbf,
                     const float* __restrict__ W_ih,
                     const float* __restrict__ W_hh,
                     const float* __restrict__ b_ih,
                     const float* __restrict__ b_hh,
                     float* __restrict__ out,
                     u16* __restrict__ hist)    // [(T_+1)][B_][H_] bf16
{
  const int lane = threadIdx.x;     // 64
  const int wg   = blockIdx.x;
  const int q    = lane >> 4;       // K-slice within chunk; j-offset in tile
  const int n    = lane & 15;       // batch col (n<8 real)
  const int nb   = n & 7;
  const int chain  = wg & 7;
  const int jgroup = wg >> 3;       // [0,64)
  const int jbase  = jgroup * JGW;
  const int bbase  = chain * NB;

  // ---- W -> register A-fragments, once. Tile mt row map (R5-verified):
  // row(m) = (m&3)*H + jbase + 4*mt + (m>>2); lane holds m=n, k=kc*32+q*8+i.
  // C comes back as acc[mt][.][r] = gate r for (j = jbase+4*mt+q, batch n).
  bf16x8 afrag[2][24];
  #pragma unroll
  for (int mt = 0; mt < 2; ++mt) {
    const int row = (n & 3) * H_ + jbase + 4 * mt + (n >> 2);
    #pragma unroll
    for (int kc = 0; kc < 24; ++kc) {
      const float* src;
      if (kc < 8) src = W_ih + (size_t)row * I_ + kc * 32 + q * 8;
      else        src = W_hh + (size_t)row * H_ + (kc - 8) * 32 + q * 8;
      float4 f0 = ((const float4*)src)[0];
      float4 f1 = ((const float4*)src)[1];
      bf16x8 a;
      a[0]=(__bf16)f0.x; a[1]=(__bf16)f0.y; a[2]=(__bf16)f0.z; a[3]=(__bf16)f0.w;
      a[4]=(__bf16)f1.x; a[5]=(__bf16)f1.y; a[6]=(__bf16)f1.z; a[7]=(__bf16)f1.w;
      afrag[mt][kc] = a;
    }
  }

  float bias[2][4];
  #pragma unroll
  for (int mt = 0; mt < 2; ++mt)
    #pragma unroll
    for (int g = 0; g < 4; ++g) {
      const int jc = jbase + 4 * mt + q;
      bias[mt][g] = b_ih[g * H_ + jc] + b_hh[g * H_ + jc];
    }
  float cval[2] = {0.0f, 0.0f};

  for (int t = 0; t < T_; ++t) {
    // ---- issue x loads first (bf16, L2/L3-cached; latency hides under poll)
    const u16* xrow = xbf + ((size_t)t * B_ + bbase + nb) * I_ + q * 8;
    uint4 xv[8];
    #pragma unroll
    for (int kc = 0; kc < 8; ++kc)
      xv[kc] = *(const uint4*)(xrow + kc * 32);

    // ---- sentinel-poll ALL 16 h-chunks of hist[t] ----
    u32x4 r[16];
    {
      const u16* hp = hist + (size_t)t * BH + (size_t)(bbase + nb) * H_ + q * 8;
      for (;;) {
        load_h16_l3(hp, r);
        u32 bad = 0;
        #pragma unroll
        for (int i = 0; i < 16; ++i)
          #pragma unroll
          for (int jj = 0; jj < 4; ++jj) bad |= (r[i][jj] == POISON);
        if (!__any((int)bad)) break;
      }
    }

    // ---- 48 MFMAs, 8 independent accumulator chains (depth 6) ----
    floatx4 acc[2][4] = {};
    #pragma unroll
    for (int kc = 0; kc < 8; ++kc) {
      bf16x8 xb = __builtin_bit_cast(bf16x8, xv[kc]);
      #pragma unroll
      for (int mt = 0; mt < 2; ++mt)
        acc[mt][kc & 3] = __builtin_amdgcn_mfma_f32_16x16x32_bf16(
            afrag[mt][kc], xb, acc[mt][kc & 3], 0, 0, 0);
    }
    #pragma unroll
    for (int kc = 8; kc < 24; ++kc) {
      bf16x8 hb = __builtin_bit_cast(bf16x8, r[kc - 8]);
      #pragma unroll
      for (int mt = 0; mt < 2; ++mt)
        acc[mt][kc & 3] = __builtin_amdgcn_mfma_f32_16x16x32_bf16(
            afrag[mt][kc], hb, acc[mt][kc & 3], 0, 0, 0);
    }

    // ---- gates complete in-lane: elementwise for the 2 j-cols ----
    float hval[2];
    #pragma unroll
    for (int mt = 0; mt < 2; ++mt) {
      float gate[4];
      #pragma unroll
      for (int g = 0; g < 4; ++g)
        gate[g] = acc[mt][0][g] + acc[mt][1][g] + acc[mt][2][g] + acc[mt][3][g]
                + bias[mt][g];
      const float ig = sigmoid_f(gate[0]);
      const float fg = sigmoid_f(gate[1]);
      const float gg = tanh_f(gate[2]);
      const float og = sigmoid_f(gate[3]);
      cval[mt] = fg * cval[mt] + ig * gg;
      hval[mt] = og * tanh_f(cval[mt]);
    }

    // ---- pack 8 cols (one batch row) into ONE dwordx4, publish ----
    // j order per batch n: mt0 q0..3 = j0..3, mt1 q0..3 = j4..7.
    const u32 hb0 = (u32)f2bf(hval[0]);
    const u32 hb1 = (u32)f2bf(hval[1]);
    const u32 o0 = (u32)__shfl_xor((int)hb0, 16, 64);   // partner q^1
    const u32 o1 = (u32)__shfl_xor((int)hb1, 16, 64);
    const u32 w0 = hb0 | (o0 << 16);                    // valid on even q
    const u32 w1 = hb1 | (o1 << 16);
    const u32 v1 = (u32)__shfl_xor((int)w0, 32, 64);    // q=0 <- q=2
    const u32 v3 = (u32)__shfl_xor((int)w1, 32, 64);
    if (q == 0 && n < 8) {
      u32x4 v4; v4[0] = w0; v4[1] = v1; v4[2] = w1; v4[3] = v3;
      store_u32x4_l3((u32*)(hist + (size_t)(t + 1) * BH +
                            (size_t)(bbase + n) * H_ + jbase), v4);
    }
    if (t == T_ - 1 && n < 8) {
      #pragma unroll
      for (int mt = 0; mt < 2; ++mt) {
        const int jc = jbase + 4 * mt + q;
        out[TBO + (size_t)(bbase + n) * H_ + jc]      = hval[mt];   // h_T
        out[TBO + BH + (size_t)(bbase + n) * H_ + jc] = cval[mt];   // c_T
      }
    }
  }
}

// outputs[t,b,:] = h_t @ fc_w^T + fc_b ; one wave per (t,b) row
__global__ __launch_bounds__(256)
void fc_kernel(const u16* __restrict__ hist,
               const float* __restrict__ fc_w,
               const float* __restrict__ fc_b,
               float* __restrict__ out)
{
  const int gw   = (blockIdx.x * 256 + threadIdx.x) >> 6;
  const int lane = threadIdx.x & 63;
  const int t = gw >> 6;
  const int b = gw & 63;
  const u16* hrow = hist + ((size_t)(t + 1) * B_ + b) * H_ + lane * 8;
  uint4 hv = *(const uint4*)hrow;
  float h[8];
  {
    u16x8 hu = __builtin_bit_cast(u16x8, hv);
    #pragma unroll
    for (int i = 0; i < 8; ++i) h[i] = bf2f(hu[i]);
  }
  float accs[O_];
  #pragma unroll
  for (int o = 0; o < O_; ++o) {
    const float* wr = fc_w + (size_t)o * H_ + lane * 8;
    float4 w0 = ((const float4*)wr)[0];
    float4 w1 = ((const float4*)wr)[1];
    accs[o] = h[0]*w0.x + h[1]*w0.y + h[2]*w0.z + h[3]*w0.w
            + h[4]*w1.x + h[5]*w1.y + h[6]*w1.z + h[7]*w1.w;
  }
  #pragma unroll
  for (int o = 0; o < O_; ++o)
    #pragma unroll
    for (int off = 32; off > 0; off >>= 1)
      accs[o] += __shfl_down(accs[o], off, 64);
  if (lane == 0) {
    #pragma unroll
    for (int o = 0; o < O_; ++o)
      out[((size_t)t * B_ + b) * O_ + o] = accs[o] + fc_b[o];
  }
}

extern "C" void kernel_launch(void* const* d_in, const int* in_sizes, int n_in,
                              void* d_out, int out_size, void* d_ws, size_t ws_size,
                              hipStream_t stream)
{
  (void)in_sizes; (void)n_in; (void)out_size; (void)ws_size;
  const float* x    = (const float*)d_in[0];
  const float* W_ih = (const float*)d_in[1];
  const float* W_hh = (const float*)d_in[2];
  const float* b_ih = (const float*)d_in[3];
  const float* b_hh = (const float*)d_in[4];
  const float* fc_w = (const float*)d_in[5];
  const float* fc_b = (const float*)d_in[6];
  float* out = (float*)d_out;

  u16* hist = (u16*)((char*)d_ws + EX_OFF);             // [(T+1)][B][H] bf16
  u16* xbf  = (u16*)((char*)d_ws + EX_OFF + HIST_BYTES); // [T][B][I] bf16

  // hist slot 0 -> h_0 = 0 (consumers pass poll instantly at t=0);
  // hist slots 1..T -> 0x7F poison (bf16 pair 0x7F7F7F7F, unreachable |h|<1)
  hipMemsetAsync((char*)d_ws + EX_OFF, 0, (size_t)BH * 2, stream);
  hipMemsetAsync((char*)d_ws + EX_OFF + (size_t)BH * 2, 0x7F,
                 (size_t)T_ * BH * 2, stream);

  xconv_kernel<<<(T_ * B_ * I_) / (256 * 8), 256, 0, stream>>>(x, xbf);
  lstm_persistent<<<GRID_MAIN, BLOCK_MAIN, 0, stream>>>(
      xbf, W_ih, W_hh, b_ih, b_hh, out, hist);
  fc_kernel<<<(T_ * B_) / 4, 256, 0, stream>>>(hist, fc_w, fc_b, out);
}

// Round 8
// 3088.495 us; speedup vs baseline: 1.9497x; 1.9497x over previous
//
#include <hip/hip_runtime.h>
#include <stdint.h>

#define T_ 1024
#define B_ 64
#define I_ 256
#define H_ 512
#define O_ 5
#define NCHAIN 4
#define NB 16            // batches per chain (MFMA N=16 fully used)
#define JW 32            // j-cols per WG
#define GRID_MAIN 64     // 4 chains x 16 WGs (chain = wg&3, jslot = wg>>2)
#define BLOCK_MAIN 512   // 8 waves: (mg in [0,2)) x (kq in [0,4))
#define XBS 264          // xbuf row stride in u16 (256 + 8 pad)
#define PS 18            // part row stride in floats (bank-clean, verified)
#define EX_OFF 4096      // hist offset in ws (bytes)
#define BH (B_*H_)
#define TBO (T_*B_*O_)
#define POISON 0x7F7F7F7Fu   // bf16 pair sentinel: |h|<1 can never encode 0x7F7F

typedef __bf16 bf16x8 __attribute__((ext_vector_type(8)));
typedef float floatx4 __attribute__((ext_vector_type(4)));
typedef unsigned short u16;
typedef unsigned short u16x8 __attribute__((ext_vector_type(8)));
typedef unsigned int u32;
typedef u32 u32x4 __attribute__((ext_vector_type(4)));

__device__ __forceinline__ u16 f2bf(float f) {
  unsigned int u = __float_as_uint(f);
  u += 0x7fffu + ((u >> 16) & 1u);   // RNE
  return (u16)(u >> 16);
}
__device__ __forceinline__ float bf2f(u16 v) {
  return __uint_as_float(((unsigned int)v) << 16);
}
__device__ __forceinline__ float sigmoid_f(float x) {
  return 1.0f / (1.0f + __expf(-x));
}
__device__ __forceinline__ float tanh_f(float x) {
  return 2.0f / (1.0f + __expf(-2.0f * x)) - 1.0f;
}

// ---- L3-coherent exchange primitives (sc0 sc1 = bypass L1/L2; coherence
// point is the memory-side Infinity Cache). R1-measured-good. Write-once +
// sentinel slots: any non-poison value read is correct; staleness can only
// look like poison -> retry.
__device__ __forceinline__ void store_u32_l3(u32* p, u32 v) {
  asm volatile("global_store_dword %0, %1, off sc0 sc1" :: "v"(p), "v"(v) : "memory");
}

// bulk B-fragment poll loads: issue all dwordx4 then ONE vmcnt (1 L3 RT).
__device__ __forceinline__ void load_h4_l3(const u16* p, u32x4* r) {
  asm volatile(
    "global_load_dwordx4 %0, %4, off sc0 sc1\n\t"
    "global_load_dwordx4 %1, %4, off offset:64 sc0 sc1\n\t"
    "global_load_dwordx4 %2, %4, off offset:128 sc0 sc1\n\t"
    "global_load_dwordx4 %3, %4, off offset:192 sc0 sc1\n\t"
    "s_waitcnt vmcnt(0)"
    : "=&v"(r[0]), "=&v"(r[1]), "=&v"(r[2]), "=&v"(r[3]) : "v"(p) : "memory");
}
__device__ __forceinline__ void load_h6_l3(const u16* p, u32x4* r) {
  asm volatile(
    "global_load_dwordx4 %0, %6, off sc0 sc1\n\t"
    "global_load_dwordx4 %1, %6, off offset:64 sc0 sc1\n\t"
    "global_load_dwordx4 %2, %6, off offset:128 sc0 sc1\n\t"
    "global_load_dwordx4 %3, %6, off offset:192 sc0 sc1\n\t"
    "global_load_dwordx4 %4, %6, off offset:256 sc0 sc1\n\t"
    "global_load_dwordx4 %5, %6, off offset:320 sc0 sc1\n\t"
    "s_waitcnt vmcnt(0)"
    : "=&v"(r[0]), "=&v"(r[1]), "=&v"(r[2]), "=&v"(r[3]), "=&v"(r[4]), "=&v"(r[5])
    : "v"(p) : "memory");
}

// LDS-only barrier: no vmcnt drain (h publish stores propagate async;
// consumers sentinel-poll until the data arrives).
__device__ __forceinline__ void barrier_lds() {
  asm volatile("s_waitcnt lgkmcnt(0)\n\ts_barrier" ::: "memory");
}

// Persistent LSTM, R8: 4 chains x 16 WGs (HALF the producers per chain of
// R1, attacking the max-over-producers skew term) x 16 batches (MFMA N=16
// fully used -> chip MFMA count halves). Every R1 micro-pattern retained:
// per wave 24 MFMAs over a K-quarter (4 M-tiles x 6 chunks, afrag 96 VGPR),
// same poll slices, part[]+PS=18 reduce, paired-u32 publish, two LDS-only
// barriers/step, sentinel L3 exchange. Publish per WG per batch row is now
// a full exclusive 64B line (32 j x 2B).
__global__ __launch_bounds__(BLOCK_MAIN, 1)
void lstm_persistent(const float* __restrict__ x,
                     const float* __restrict__ W_ih,
                     const float* __restrict__ W_hh,
                     const float* __restrict__ b_ih,
                     const float* __restrict__ b_hh,
                     float* __restrict__ out,
                     u16* __restrict__ hist)    // [(T_+1)][B_][H_] bf16
{
  __shared__ __align__(16) u16 xbuf[2][NB][XBS];        // 16.9 KB
  __shared__ float part[4 * 8 * 16 * PS];               // 36 KB [kq][mt][j][n]

  const int tid  = threadIdx.x;
  const int wg   = blockIdx.x;
  const int w    = tid >> 6;        // wave id
  const int lane = tid & 63;
  const int q    = lane >> 4;       // K-slice within chunk / C row-group
  const int n    = lane & 15;       // batch col (ALL 16 real)
  const int kq   = w & 3;           // K-quarter (6 chunks of 32)
  const int mg   = w >> 2;          // gate-pair group: gates 2mg, 2mg+1
  const int chain = wg & 3;
  const int jslot = wg >> 2;
  const int jbase = jslot * JW;
  const int bbase = chain * NB;

  // ---- W -> register A-fragments (A[m=lane&15][k=q*8+i]), once ----
  // M-tile (g, jt): weight rows g*H + jbase + jt*16 + [0,16)
  bf16x8 afrag[2][2][6];
  #pragma unroll
  for (int gp = 0; gp < 2; ++gp) {
    #pragma unroll
    for (int jt = 0; jt < 2; ++jt) {
      const int row = (2 * mg + gp) * H_ + jbase + jt * 16 + n;
      #pragma unroll
      for (int kk = 0; kk < 6; ++kk) {
        const int kc = kq * 6 + kk;               // K-chunk of 32
        const float* src;
        if (kc < 8) src = W_ih + (size_t)row * I_ + kc * 32 + q * 8;
        else        src = W_hh + (size_t)row * H_ + (kc - 8) * 32 + q * 8;
        float4 f0 = ((const float4*)src)[0];
        float4 f1 = ((const float4*)src)[1];
        bf16x8 a;
        a[0]=(__bf16)f0.x; a[1]=(__bf16)f0.y; a[2]=(__bf16)f0.z; a[3]=(__bf16)f0.w;
        a[4]=(__bf16)f1.x; a[5]=(__bf16)f1.y; a[6]=(__bf16)f1.z; a[7]=(__bf16)f1.w;
        afrag[gp][jt][kk] = a;
      }
    }
  }

  // ---- elementwise identity: EVERY thread owns one (j = tid>>4, n = tid&15)
  const int rj = tid >> 4;          // [0,32) j within WG
  const int rn = tid & 15;          // batch
  const int jt_r = rj >> 4, jr = rj & 15;
  float bias[4];
  #pragma unroll
  for (int g = 0; g < 4; ++g)
    bias[g] = b_ih[g * H_ + jbase + rj] + b_hh[g * H_ + jbase + rj];
  float cval = 0.0f;

  const int nx   = (kq == 0) ? 6 : ((kq == 1) ? 2 : 0);
  const int hoff = (kq == 2) ? 128 : ((kq == 3) ? 320 : 0);  // first h j-index

  // ---- x staging identity: one 8-float chunk per thread (16 b x 32 chunks)
  const int sb  = tid >> 5;         // batch [0,16)
  const int sko = (tid & 31) * 8;   // col offset
  float4 px[2];

  // ---- prologue: x_0 -> LDS (direct), x_1 -> prefetch regs (R4 pattern) ----
  {
    const float* s0 = x + ((size_t)bbase + sb) * I_ + sko;
    float4 f0 = ((const float4*)s0)[0], f1 = ((const float4*)s0)[1];
    u16x8 uu;
    uu[0]=f2bf(f0.x); uu[1]=f2bf(f0.y); uu[2]=f2bf(f0.z); uu[3]=f2bf(f0.w);
    uu[4]=f2bf(f1.x); uu[5]=f2bf(f1.y); uu[6]=f2bf(f1.z); uu[7]=f2bf(f1.w);
    *(u16x8*)&xbuf[0][sb][sko] = uu;
    const float* s1 = x + ((size_t)B_ + bbase + sb) * I_ + sko;
    px[0] = ((const float4*)s1)[0];
    px[1] = ((const float4*)s1)[1];
  }
  __syncthreads();

  for (int t = 0; t < T_; ++t) {
    const int sr = t & 1, sw = sr ^ 1;

    bf16x8 bfrag[6];
    #pragma unroll
    for (int kk = 0; kk < 6; ++kk)
      if (kk < nx)
        bfrag[kk] = __builtin_bit_cast(bf16x8,
            *(const uint4*)&xbuf[sr][n][(kq * 6 + kk) * 32 + q * 8]);

    if (kq > 0) {
      // sentinel-poll this K-quarter's h slice from hist[t] — 1 L3 RT/try
      const u16* hp = hist + (size_t)t * BH + (size_t)(bbase + n) * H_ +
                      hoff + q * 8;
      if (kq == 1) {
        u32x4 r[4];
        for (;;) {
          load_h4_l3(hp, r);
          u32 bad = 0;
          #pragma unroll
          for (int i = 0; i < 4; ++i)
            #pragma unroll
            for (int jj = 0; jj < 4; ++jj) bad |= (r[i][jj] == POISON);
          if (!__any((int)bad)) break;
        }
        #pragma unroll
        for (int i = 0; i < 4; ++i)
          bfrag[2 + i] = __builtin_bit_cast(bf16x8, r[i]);
      } else {
        u32x4 r[6];
        for (;;) {
          load_h6_l3(hp, r);
          u32 bad = 0;
          #pragma unroll
          for (int i = 0; i < 6; ++i)
            #pragma unroll
            for (int jj = 0; jj < 4; ++jj) bad |= (r[i][jj] == POISON);
          if (!__any((int)bad)) break;
        }
        #pragma unroll
        for (int i = 0; i < 6; ++i)
          bfrag[i] = __builtin_bit_cast(bf16x8, r[i]);
      }
    }

    // ---- MFMA: 4 M-tiles x 6 K-chunks = 24 (same per-wave load as R1) ----
    floatx4 acc[2][2] = {};
    #pragma unroll
    for (int kk = 0; kk < 6; ++kk) {
      #pragma unroll
      for (int gp = 0; gp < 2; ++gp)
        #pragma unroll
        for (int jt = 0; jt < 2; ++jt)
          acc[gp][jt] = __builtin_amdgcn_mfma_f32_16x16x32_bf16(
              afrag[gp][jt][kk], bfrag[kk], acc[gp][jt], 0, 0, 0);
    }

    // write partial C tiles (C: col=lane&15=batch, row=q*4+reg=j16)
    // PS=18: banks (8q + n) % 32 -> exactly 2-way = free
    #pragma unroll
    for (int gp = 0; gp < 2; ++gp)
      #pragma unroll
      for (int jt = 0; jt < 2; ++jt)
        #pragma unroll
        for (int r = 0; r < 4; ++r)
          part[((kq * 8 + (2 * mg + gp) * 2 + jt) * 16 + q * 4 + r) * PS + n]
              = acc[gp][jt][r];
    barrier_lds();

    // ---- ALL threads: reduce 4 K-partials for own (rj, rn); publish ----
    float gate[4];
    #pragma unroll
    for (int g = 0; g < 4; ++g) {
      float s = bias[g];
      #pragma unroll
      for (int k2 = 0; k2 < 4; ++k2)
        s += part[((k2 * 8 + g * 2 + jt_r) * 16 + jr) * PS + rn];
      gate[g] = s;
    }
    const float ig = sigmoid_f(gate[0]);
    const float fg = sigmoid_f(gate[1]);
    const float gg = tanh_f(gate[2]);
    const float og = sigmoid_f(gate[3]);
    cval = fg * cval + ig * gg;
    const float hval = og * tanh_f(cval);

    // pair j (rj) with rj^1 via lane^16 shuffle; even-rj thread stores u32
    const u32 hb = (u32)f2bf(hval);
    const u32 other = (u32)__shfl_xor((int)hb, 16, 64);
    if ((rj & 1) == 0) {
      const u32 packed = hb | (other << 16);
      store_u32_l3((u32*)(hist + (size_t)(t + 1) * BH +
                          (size_t)(bbase + rn) * H_ + jbase + rj), packed);
    }
    if (t == T_ - 1) {
      out[TBO + (size_t)(bbase + rn) * H_ + jbase + rj]      = hval;  // h_T
      out[TBO + BH + (size_t)(bbase + rn) * H_ + jbase + rj] = cval;  // c_T
    }

    // ---- async-split x staging: write x_{t+1} (loaded a step ago),
    // issue x_{t+2} (waited a full step later)
    {
      u16x8 uu;
      const float4 f0 = px[0], f1 = px[1];
      uu[0]=f2bf(f0.x); uu[1]=f2bf(f0.y); uu[2]=f2bf(f0.z); uu[3]=f2bf(f0.w);
      uu[4]=f2bf(f1.x); uu[5]=f2bf(f1.y); uu[6]=f2bf(f1.z); uu[7]=f2bf(f1.w);
      *(u16x8*)&xbuf[sw][sb][sko] = uu;
      const int ts2 = (t + 2 < T_) ? (t + 2) : (T_ - 1);
      const float* s = x + ((size_t)ts2 * B_ + bbase + sb) * I_ + sko;
      px[0] = ((const float4*)s)[0];
      px[1] = ((const float4*)s)[1];
    }
    barrier_lds();   // LDS-only: h stores drain asynchronously toward L3
  }
}

// outputs[t,b,:] = h_t @ fc_w^T + fc_b ; one wave per (t,b) row
__global__ __launch_bounds__(256)
void fc_kernel(const u16* __restrict__ hist,
               const float* __restrict__ fc_w,
               const float* __restrict__ fc_b,
               float* __restrict__ out)
{
  const int gw   = (blockIdx.x * 256 + threadIdx.x) >> 6;
  const int lane = threadIdx.x & 63;
  const int t = gw >> 6;
  const int b = gw & 63;
  const u16* hrow = hist + ((size_t)(t + 1) * B_ + b) * H_ + lane * 8;
  uint4 hv = *(const uint4*)hrow;
  float h[8];
  {
    u16x8 hu = __builtin_bit_cast(u16x8, hv);
    #pragma unroll
    for (int i = 0; i < 8; ++i) h[i] = bf2f(hu[i]);
  }
  float accs[O_];
  #pragma unroll
  for (int o = 0; o < O_; ++o) {
    const float* wr = fc_w + (size_t)o * H_ + lane * 8;
    float4 w0 = ((const float4*)wr)[0];
    float4 w1 = ((const float4*)wr)[1];
    accs[o] = h[0]*w0.x + h[1]*w0.y + h[2]*w0.z + h[3]*w0.w
            + h[4]*w1.x + h[5]*w1.y + h[6]*w1.z + h[7]*w1.w;
  }
  #pragma unroll
  for (int o = 0; o < O_; ++o)
    #pragma unroll
    for (int off = 32; off > 0; off >>= 1)
      accs[o] += __shfl_down(accs[o], off, 64);
  if (lane == 0) {
    #pragma unroll
    for (int o = 0; o < O_; ++o)
      out[((size_t)t * B_ + b) * O_ + o] = accs[o] + fc_b[o];
  }
}

extern "C" void kernel_launch(void* const* d_in, const int* in_sizes, int n_in,
                              void* d_out, int out_size, void* d_ws, size_t ws_size,
                              hipStream_t stream)
{
  (void)in_sizes; (void)n_in; (void)out_size; (void)ws_size;
  const float* x    = (const float*)d_in[0];
  const float* W_ih = (const float*)d_in[1];
  const float* W_hh = (const float*)d_in[2];
  const float* b_ih = (const float*)d_in[3];
  const float* b_hh = (const float*)d_in[4];
  const float* fc_w = (const float*)d_in[5];
  const float* fc_b = (const float*)d_in[6];
  float* out = (float*)d_out;

  u16* hist = (u16*)((char*)d_ws + EX_OFF);             // [(T+1)][B][H] bf16

  // hist slot 0 -> h_0 = 0 (consumers pass poll instantly at t=0);
  // hist slots 1..T -> 0x7F poison (bf16 pair 0x7F7F7F7F, unreachable |h|<1)
  hipMemsetAsync((char*)d_ws + EX_OFF, 0, (size_t)BH * 2, stream);
  hipMemsetAsync((char*)d_ws + EX_OFF + (size_t)BH * 2, 0x7F,
                 (size_t)T_ * BH * 2, stream);

  lstm_persistent<<<GRID_MAIN, BLOCK_MAIN, 0, stream>>>(
      x, W_ih, W_hh, b_ih, b_hh, out, hist);
  fc_kernel<<<(T_ * B_) / 4, 256, 0, stream>>>(hist, fc_w, fc_b, out);
}

// Round 9
// 2458.636 us; speedup vs baseline: 2.4492x; 1.2562x over previous
//
#include <hip/hip_runtime.h>
#include <stdint.h>

#define T_ 1024
#define B_ 64
#define I_ 256
#define H_ 512
#define O_ 5
#define NB 8             // batches per chain
#define JW 16            // hidden columns per WG
#define GRID_MAIN 256    // 8 chains x 32 WGs (chain = wg&7, jslot = wg>>3)
#define BLOCK_MAIN 256
#define XBS 264          // xbuf row stride in u16 (256 + 8 pad)
#define PS 18            // part row stride in floats (bank-clean, verified)
#define EX_OFF 4096      // hist offset in ws (bytes)
#define BH (B_*H_)
#define TBO (T_*B_*O_)
#define POISON 0x7F7F7F7Fu   // bf16 pair sentinel: |h|<1 can never encode 0x7F7F

typedef __bf16 bf16x8 __attribute__((ext_vector_type(8)));
typedef float floatx4 __attribute__((ext_vector_type(4)));
typedef unsigned short u16;
typedef unsigned short u16x8 __attribute__((ext_vector_type(8)));
typedef unsigned int u32;
typedef u32 u32x4 __attribute__((ext_vector_type(4)));

__device__ __forceinline__ u16 f2bf(float f) {
  unsigned int u = __float_as_uint(f);
  u += 0x7fffu + ((u >> 16) & 1u);   // RNE
  return (u16)(u >> 16);
}
__device__ __forceinline__ float bf2f(u16 v) {
  return __uint_as_float(((unsigned int)v) << 16);
}
__device__ __forceinline__ float sigmoid_f(float x) {
  return 1.0f / (1.0f + __expf(-x));
}
__device__ __forceinline__ float tanh_f(float x) {
  return 2.0f / (1.0f + __expf(-2.0f * x)) - 1.0f;
}

// ---- L3-coherent exchange primitives (sc0 sc1 = bypass L1/L2; coherence
// point is the memory-side Infinity Cache). Write-once + sentinel slots:
// any non-poison value read is correct; staleness can only look like
// poison -> retry. R9's ONE change vs the R4/R1 kernel: the poll loops
// back off (s_sleep) between failed tries — ~96 spinning waves/chain x
// ~48 L3 lines/try was a multi-TB/s parasitic load on the Infinity Cache
// (congestion hypothesis: R7's 2x poll traffic -> 2.9x time; detect term
// ~2500cy >> quiet L3 RT).
__device__ __forceinline__ void store_u32_l3(u32* p, u32 v) {
  asm volatile("global_store_dword %0, %1, off sc0 sc1" :: "v"(p), "v"(v) : "memory");
}

// bulk B-fragment poll loads: issue all dwordx4 then ONE vmcnt (1 L3 RT).
__device__ __forceinline__ void load_h4_l3(const u16* p, u32x4* r) {
  asm volatile(
    "global_load_dwordx4 %0, %4, off sc0 sc1\n\t"
    "global_load_dwordx4 %1, %4, off offset:64 sc0 sc1\n\t"
    "global_load_dwordx4 %2, %4, off offset:128 sc0 sc1\n\t"
    "global_load_dwordx4 %3, %4, off offset:192 sc0 sc1\n\t"
    "s_waitcnt vmcnt(0)"
    : "=&v"(r[0]), "=&v"(r[1]), "=&v"(r[2]), "=&v"(r[3]) : "v"(p) : "memory");
}
__device__ __forceinline__ void load_h6_l3(const u16* p, u32x4* r) {
  asm volatile(
    "global_load_dwordx4 %0, %6, off sc0 sc1\n\t"
    "global_load_dwordx4 %1, %6, off offset:64 sc0 sc1\n\t"
    "global_load_dwordx4 %2, %6, off offset:128 sc0 sc1\n\t"
    "global_load_dwordx4 %3, %6, off offset:192 sc0 sc1\n\t"
    "global_load_dwordx4 %4, %6, off offset:256 sc0 sc1\n\t"
    "global_load_dwordx4 %5, %6, off offset:320 sc0 sc1\n\t"
    "s_waitcnt vmcnt(0)"
    : "=&v"(r[0]), "=&v"(r[1]), "=&v"(r[2]), "=&v"(r[3]), "=&v"(r[4]), "=&v"(r[5])
    : "v"(p) : "memory");
}

// LDS-only barrier: no vmcnt drain (h publish stores propagate async;
// consumers sentinel-poll until the data arrives).
__device__ __forceinline__ void barrier_lds() {
  asm volatile("s_waitcnt lgkmcnt(0)\n\ts_barrier" ::: "memory");
}

// stage bf16(x[ts]) slice (8 batches x 256) into LDS xbuf slot; u in [0,128)
// (prologue only — in-loop staging is the async-split pair below)
__device__ __forceinline__ void stage_x(const float* __restrict__ xsrc,
                                        u16 (*xb)[XBS], int u) {
  #pragma unroll
  for (int i = 0; i < 2; ++i) {
    int cid = u + 128 * i;          // 256 chunks of 8 floats
    int b  = cid >> 5;
    int ko = (cid & 31) * 8;
    const float4* s = (const float4*)(xsrc + (size_t)b * I_ + ko);
    float4 f0 = s[0], f1 = s[1];
    u16x8 uu;
    uu[0]=f2bf(f0.x); uu[1]=f2bf(f0.y); uu[2]=f2bf(f0.z); uu[3]=f2bf(f0.w);
    uu[4]=f2bf(f1.x); uu[5]=f2bf(f1.y); uu[6]=f2bf(f1.z); uu[7]=f2bf(f1.w);
    *(u16x8*)&xb[b][ko] = uu;
  }
}

// ---- async-split x staging (R4, measured neutral-safe): issue loads one
// step early (16 VGPRs), convert+ds_write a full step later.
__device__ __forceinline__ void xpf_issue(const float* __restrict__ xsrc,
                                          int u, float4* px) {
  #pragma unroll
  for (int i = 0; i < 2; ++i) {
    const int cid = u + 128 * i;
    const int b  = cid >> 5;
    const int ko = (cid & 31) * 8;
    const float4* s = (const float4*)(xsrc + (size_t)b * I_ + ko);
    px[2 * i]     = s[0];
    px[2 * i + 1] = s[1];
  }
}
__device__ __forceinline__ void xpf_write(u16 (*xb)[XBS], int u,
                                          const float4* px) {
  #pragma unroll
  for (int i = 0; i < 2; ++i) {
    const int cid = u + 128 * i;
    const int b  = cid >> 5;
    const int ko = (cid & 31) * 8;
    const float4 f0 = px[2 * i], f1 = px[2 * i + 1];
    u16x8 uu;
    uu[0]=f2bf(f0.x); uu[1]=f2bf(f0.y); uu[2]=f2bf(f0.z); uu[3]=f2bf(f0.w);
    uu[4]=f2bf(f1.x); uu[5]=f2bf(f1.y); uu[6]=f2bf(f1.z); uu[7]=f2bf(f1.w);
    *(u16x8*)&xb[b][ko] = uu;
  }
}

// Persistent LSTM, 8 chains x 32 WGs — R1 structure (measured-best):
// two LDS-only barriers/step, scalar paired-u32 publish (32B/wave/row,
// sector-clean), pure-L3 sentinel polls, PS=18, reg-prefetch x staging.
// R9's single variable: backoff ladder in the poll loops.
__global__ __launch_bounds__(BLOCK_MAIN, 1)
void lstm_persistent(const float* __restrict__ x,
                     const float* __restrict__ W_ih,
                     const float* __restrict__ W_hh,
                     const float* __restrict__ b_ih,
                     const float* __restrict__ b_hh,
                     float* __restrict__ out,
                     u16* __restrict__ hist)    // [(T_+1)][B_][H_] bf16
{
  __shared__ __align__(16) u16 xbuf[2][NB][XBS];
  __shared__ float part[16 * 16 * PS];

  const int tid  = threadIdx.x;
  const int wg   = blockIdx.x;
  const int w    = tid >> 6;        // wave id = K-quarter
  const int lane = tid & 63;
  const int q    = lane >> 4;
  const int n    = lane & 15;
  const int chain = wg & 7;
  const int jslot = wg >> 3;
  const int jbase = jslot * JW;
  const int bbase = chain * NB;

  // ---- W -> register A-fragments (A[m=lane&15][k=q*8+i]), once ----
  bf16x8 afrag[4][6];
  #pragma unroll
  for (int g = 0; g < 4; ++g) {
    #pragma unroll
    for (int kk = 0; kk < 6; ++kk) {
      const int kc  = w * 6 + kk;                 // K-chunk of 32
      const int row = g * H_ + jbase + n;         // gate row in [0,2048)
      const float* src;
      if (kc < 8) src = W_ih + (size_t)row * I_ + kc * 32 + q * 8;
      else        src = W_hh + (size_t)row * H_ + (kc - 8) * 32 + q * 8;
      float4 f0 = ((const float4*)src)[0];
      float4 f1 = ((const float4*)src)[1];
      bf16x8 a;
      a[0]=(__bf16)f0.x; a[1]=(__bf16)f0.y; a[2]=(__bf16)f0.z; a[3]=(__bf16)f0.w;
      a[4]=(__bf16)f1.x; a[5]=(__bf16)f1.y; a[6]=(__bf16)f1.z; a[7]=(__bf16)f1.w;
      afrag[g][kk] = a;
    }
  }

  // ---- elementwise identity: threads 0..127 own (eb in [0,8), ej in [0,16)) ----
  const int eb = tid >> 4;
  const int ej = tid & 15;
  float bias[4];
  float cval = 0.0f;
  if (tid < 128) {
    #pragma unroll
    for (int g = 0; g < 4; ++g)
      bias[g] = b_ih[g * H_ + jbase + ej] + b_hh[g * H_ + jbase + ej];
  }

  const int nx   = (w == 0) ? 6 : ((w == 1) ? 2 : 0);
  const int hoff = (w == 2) ? 128 : ((w == 3) ? 320 : 0);  // first h j-index

  // ---- prologue: x_0 -> LDS (sync), x_1 -> prefetch regs ----
  const int u = tid - 128;
  float4 px[4];
  if (tid >= 128) {
    stage_x(x + (size_t)bbase * I_, xbuf[0], u);
    xpf_issue(x + ((size_t)1 * B_ + bbase) * I_, u, px);
  }
  __syncthreads();

  for (int t = 0; t < T_; ++t) {
    const int sr = t & 1, sw = sr ^ 1;

    bf16x8 bfrag[6];
    #pragma unroll
    for (int kk = 0; kk < 6; ++kk)
      if (kk < nx)
        bfrag[kk] = __builtin_bit_cast(bf16x8,
            *(const uint4*)&xbuf[sr][n & 7][(w * 6 + kk) * 32 + q * 8]);

    if (w > 0) {
      // sentinel-poll the h fragment from hist[t] with BACKOFF:
      // 1st retry waits ~256cy, later retries ~128cy -> ~3x less parasitic
      // L3 load while the data is not yet there.
      const u16* hp = hist + (size_t)t * BH + (size_t)(bbase + (n & 7)) * H_ +
                      hoff + q * 8;
      if (w == 1) {
        u32x4 r[4];
        int tries = 0;
        for (;;) {
          load_h4_l3(hp, r);
          u32 bad = 0;
          #pragma unroll
          for (int i = 0; i < 4; ++i)
            #pragma unroll
            for (int jj = 0; jj < 4; ++jj) bad |= (r[i][jj] == POISON);
          if (!__any((int)bad)) break;
          if (tries == 0) __builtin_amdgcn_s_sleep(4);
          else            __builtin_amdgcn_s_sleep(2);
          ++tries;
        }
        #pragma unroll
        for (int i = 0; i < 4; ++i)
          bfrag[2 + i] = __builtin_bit_cast(bf16x8, r[i]);
      } else {
        u32x4 r[6];
        int tries = 0;
        for (;;) {
          load_h6_l3(hp, r);
          u32 bad = 0;
          #pragma unroll
          for (int i = 0; i < 6; ++i)
            #pragma unroll
            for (int jj = 0; jj < 4; ++jj) bad |= (r[i][jj] == POISON);
          if (!__any((int)bad)) break;
          if (tries == 0) __builtin_amdgcn_s_sleep(4);
          else            __builtin_amdgcn_s_sleep(2);
          ++tries;
        }
        #pragma unroll
        for (int i = 0; i < 6; ++i)
          bfrag[i] = __builtin_bit_cast(bf16x8, r[i]);
      }
    }

    // ---- MFMA partial gates over this wave's K-quarter ----
    floatx4 acc[4] = {};
    #pragma unroll
    for (int kk = 0; kk < 6; ++kk) {
      #pragma unroll
      for (int g = 0; g < 4; ++g)
        acc[g] = __builtin_amdgcn_mfma_f32_16x16x32_bf16(afrag[g][kk], bfrag[kk], acc[g], 0, 0, 0);
    }

    // write partial C tiles (C: col=lane&15=batch, row=q*4+reg=j)
    // PS=18: write banks (8q+n)%32 = 2-way (free); read banks 2-way (free)
    #pragma unroll
    for (int g = 0; g < 4; ++g)
      #pragma unroll
      for (int r = 0; r < 4; ++r)
        part[((w * 4 + g) * 16 + (q * 4 + r)) * PS + n] = acc[g][r];
    barrier_lds();

    if (tid < 128) {
      // ---- reduce 4 K-partials, gates -> c,h ; publish h (u32-paired) ----
      float gate[4];
      #pragma unroll
      for (int g = 0; g < 4; ++g) {
        float s = bias[g];
        #pragma unroll
        for (int w2 = 0; w2 < 4; ++w2)
          s += part[((w2 * 4 + g) * 16 + ej) * PS + eb];
        gate[g] = s;
      }
      const float ig = sigmoid_f(gate[0]);
      const float fg = sigmoid_f(gate[1]);
      const float gg = tanh_f(gate[2]);
      const float og = sigmoid_f(gate[3]);
      cval = fg * cval + ig * gg;
      const float hval = og * tanh_f(cval);
      const int bg = bbase + eb;
      const int jg = jbase + ej;
      // pair adjacent ej via shuffle; even thread stores the u32 (the store
      // IS the publish — consumers poll for non-sentinel; no drain needed)
      const u32 hb = (u32)f2bf(hval);
      const u32 other = __shfl_xor((int)hb, 1, 64);
      if ((tid & 1) == 0) {
        const u32 packed = hb | (other << 16);
        store_u32_l3((u32*)(hist + (size_t)(t + 1) * BH + (size_t)bg * H_ + jg), packed);
      }
      if (t == T_ - 1) {
        out[TBO + (size_t)bg * H_ + jg]      = hval;   // h_T
        out[TBO + BH + (size_t)bg * H_ + jg] = cval;   // c_T
      }
    } else {
      // ---- waves 2,3 mid-window: drain prefetched x[t+1] (ds_write only),
      // then issue prefetch of x[t+2] (waited a full step later).
      xpf_write(xbuf[sw], u, px);
      const int ts2 = (t + 2 < T_) ? (t + 2) : (T_ - 1);
      xpf_issue(x + ((size_t)ts2 * B_ + bbase) * I_, u, px);
    }
    barrier_lds();   // LDS-only: h stores drain asynchronously toward L3
  }
}

// outputs[t,b,:] = h_t @ fc_w^T + fc_b ; one wave per (t,b) row
__global__ __launch_bounds__(256)
void fc_kernel(const u16* __restrict__ hist,
               const float* __restrict__ fc_w,
               const float* __restrict__ fc_b,
               float* __restrict__ out)
{
  const int gw   = (blockIdx.x * 256 + threadIdx.x) >> 6;
  const int lane = threadIdx.x & 63;
  const int t = gw >> 6;
  const int b = gw & 63;
  const u16* hrow = hist + ((size_t)(t + 1) * B_ + b) * H_ + lane * 8;
  uint4 hv = *(const uint4*)hrow;
  float h[8];
  {
    u16x8 hu = __builtin_bit_cast(u16x8, hv);
    #pragma unroll
    for (int i = 0; i < 8; ++i) h[i] = bf2f(hu[i]);
  }
  float accs[O_];
  #pragma unroll
  for (int o = 0; o < O_; ++o) {
    const float* wr = fc_w + (size_t)o * H_ + lane * 8;
    float4 w0 = ((const float4*)wr)[0];
    float4 w1 = ((const float4*)wr)[1];
    accs[o] = h[0]*w0.x + h[1]*w0.y + h[2]*w0.z + h[3]*w0.w
            + h[4]*w1.x + h[5]*w1.y + h[6]*w1.z + h[7]*w1.w;
  }
  #pragma unroll
  for (int o = 0; o < O_; ++o)
    #pragma unroll
    for (int off = 32; off > 0; off >>= 1)
      accs[o] += __shfl_down(accs[o], off, 64);
  if (lane == 0) {
    #pragma unroll
    for (int o = 0; o < O_; ++o)
      out[((size_t)t * B_ + b) * O_ + o] = accs[o] + fc_b[o];
  }
}

extern "C" void kernel_launch(void* const* d_in, const int* in_sizes, int n_in,
                              void* d_out, int out_size, void* d_ws, size_t ws_size,
                              hipStream_t stream)
{
  (void)in_sizes; (void)n_in; (void)out_size; (void)ws_size;
  const float* x    = (const float*)d_in[0];
  const float* W_ih = (const float*)d_in[1];
  const float* W_hh = (const float*)d_in[2];
  const float* b_ih = (const float*)d_in[3];
  const float* b_hh = (const float*)d_in[4];
  const float* fc_w = (const float*)d_in[5];
  const float* fc_b = (const float*)d_in[6];
  float* out = (float*)d_out;

  u16* hist = (u16*)((char*)d_ws + EX_OFF);             // [(T+1)][B][H] bf16

  // hist slot 0 -> h_0 = 0 (consumers pass poll instantly at t=0);
  // hist slots 1..T -> 0x7F poison (bf16 pair 0x7F7F7F7F, unreachable |h|<1)
  hipMemsetAsync((char*)d_ws + EX_OFF, 0, (size_t)BH * 2, stream);
  hipMemsetAsync((char*)d_ws + EX_OFF + (size_t)BH * 2, 0x7F,
                 (size_t)T_ * BH * 2, stream);

  lstm_persistent<<<GRID_MAIN, BLOCK_MAIN, 0, stream>>>(
      x, W_ih, W_hh, b_ih, b_hh, out, hist);
  fc_kernel<<<(T_ * B_) / 4, 256, 0, stream>>>(hist, fc_w, fc_b, out);
}